// Round 4
// baseline (26.062 us; speedup 1.0000x reference)
//
#include <hip/hip_runtime.h>

// y[row] = (sum over elements e>=1 of W[e-1]) / (count of elements >=1) + b
// rna_data: (B, S) int32 in [0, 64]; W: 64 floats; b: scalar; out: (B,) f32.
//
// One 64-lane wave per row, 4 rows per 256-thread block.
// Each lane loads NV=S/256 int4 vectors up-front (all in flight), gathers
// W from LDS, then a pure shuffle reduction (no block barrier on the hot path).
// Plain (cached) loads: the 128 MiB input fits in the 256 MiB Infinity Cache,
// so graph replays can be served from L3 above HBM bandwidth.

template<int NV>
__global__ __launch_bounds__(256) void codon_rows_kernel(
    const int* __restrict__ rna,
    const float* __restrict__ W,
    const float* __restrict__ b,
    float* __restrict__ out,
    int S)
{
    __shared__ float Wl[64];
    const int t = threadIdx.x;
    if (t < 64) Wl[t] = W[t];
    __syncthreads();

    const int wave = t >> 6;
    const int lane = t & 63;
    const int row  = blockIdx.x * 4 + wave;

    const int4* p = reinterpret_cast<const int4*>(rna + (size_t)row * (size_t)S);

    int4 v[NV];
    #pragma unroll
    for (int k = 0; k < NV; ++k)
        v[k] = p[lane + 64 * k];

    float sum = 0.0f;
    int   cnt = 0;
    #pragma unroll
    for (int k = 0; k < NV; ++k) {
        int e;
        e = v[k].x; if (e > 0) { sum += Wl[e - 1]; ++cnt; }
        e = v[k].y; if (e > 0) { sum += Wl[e - 1]; ++cnt; }
        e = v[k].z; if (e > 0) { sum += Wl[e - 1]; ++cnt; }
        e = v[k].w; if (e > 0) { sum += Wl[e - 1]; ++cnt; }
    }

    // 64-lane wave reduction (no LDS, no barrier)
    #pragma unroll
    for (int off = 32; off > 0; off >>= 1) {
        sum += __shfl_down(sum, off, 64);
        cnt += __shfl_down(cnt, off, 64);
    }

    if (lane == 0)
        out[row] = sum / (float)cnt + b[0];
}

// Generic fallback (any S, any B): one block per row, runtime loop.
__global__ __launch_bounds__(256) void codon_freq_dot_kernel(
    const int* __restrict__ rna,
    const float* __restrict__ W,
    const float* __restrict__ b,
    float* __restrict__ out,
    int S)
{
    __shared__ float Wl[64];
    __shared__ float psum[4];
    __shared__ int   pcnt[4];

    const int row = blockIdx.x;
    const int t   = threadIdx.x;

    if (t < 64) Wl[t] = W[t];
    __syncthreads();

    const int* base = rna + (size_t)row * (size_t)S;

    float sum = 0.0f;
    int   cnt = 0;

    if ((S & 3) == 0) {
        const int4* p = reinterpret_cast<const int4*>(base);
        const int nvec = S >> 2;
        for (int i = t; i < nvec; i += 256) {
            int4 v = p[i];
            int e;
            e = v.x; if (e > 0) { sum += Wl[e - 1]; ++cnt; }
            e = v.y; if (e > 0) { sum += Wl[e - 1]; ++cnt; }
            e = v.z; if (e > 0) { sum += Wl[e - 1]; ++cnt; }
            e = v.w; if (e > 0) { sum += Wl[e - 1]; ++cnt; }
        }
    } else {
        for (int i = t; i < S; i += 256) {
            int e = base[i];
            if (e > 0) { sum += Wl[e - 1]; ++cnt; }
        }
    }

    #pragma unroll
    for (int off = 32; off > 0; off >>= 1) {
        sum += __shfl_down(sum, off, 64);
        cnt += __shfl_down(cnt, off, 64);
    }

    const int wave = t >> 6;
    const int lane = t & 63;
    if (lane == 0) { psum[wave] = sum; pcnt[wave] = cnt; }
    __syncthreads();

    if (t == 0) {
        float s = psum[0] + psum[1] + psum[2] + psum[3];
        int   c = pcnt[0] + pcnt[1] + pcnt[2] + pcnt[3];
        out[row] = s / (float)c + b[0];
    }
}

extern "C" void kernel_launch(void* const* d_in, const int* in_sizes, int n_in,
                              void* d_out, int out_size, void* d_ws, size_t ws_size,
                              hipStream_t stream) {
    const int*   rna = (const int*)d_in[0];
    // d_in[1] = tissue_id -- unused by the reference computation
    const float* W   = (const float*)d_in[2];
    const float* b   = (const float*)d_in[3];
    float*       out = (float*)d_out;

    const int B = out_size;              // 16384 rows (output is (B,1))
    const int S = in_sizes[0] / B;       // 2048 codons per row

    if (S == 2048 && (B & 3) == 0) {
        // 8 int4 per lane, 1 wave per row, 4 rows per block
        codon_rows_kernel<8><<<B / 4, 256, 0, stream>>>(rna, W, b, out, S);
    } else {
        codon_freq_dot_kernel<<<B, 256, 0, stream>>>(rna, W, b, out, S);
    }
}

// Round 5
// 23.803 us; speedup vs baseline: 1.0949x; 1.0949x over previous
//
#include <hip/hip_runtime.h>

// y[row] = (sum over elements e>=1 of W[e-1]) / (count of elements >=1) + b
// rna_data: (B, S) int32 in [0, 64]; W: 64 floats; b: scalar; out: (B,) f32.
//
// One 64-lane wave per row, 4 rows per 256-thread block.
// - NT int4 loads (R3-proven best; plain cached loads regressed in R4)
// - branchless gather via extended table W2[65] (W2[0]=0)
// - nonzero count on the SCALAR pipe via ballot+popcount (wave-uniform)
// - shuffle reduction for sum only

typedef int int4v __attribute__((ext_vector_type(4)));

template<int NV>
__global__ __launch_bounds__(256) void codon_rows_kernel(
    const int* __restrict__ rna,
    const float* __restrict__ W,
    const float* __restrict__ b,
    float* __restrict__ out,
    int S)
{
    __shared__ float W2[65];   // W2[0]=0, W2[e]=W[e-1]
    const int t = threadIdx.x;
    if (t == 0) W2[0] = 0.0f;
    if (t < 64) W2[t + 1] = W[t];
    __syncthreads();

    const int wave = t >> 6;
    const int lane = t & 63;
    const int row  = blockIdx.x * 4 + wave;

    const int4v* p = reinterpret_cast<const int4v*>(rna + (size_t)row * (size_t)S);

    int4v v[NV];
    #pragma unroll
    for (int k = 0; k < NV; ++k)
        v[k] = __builtin_nontemporal_load(&p[lane + 64 * k]);

    float sum = 0.0f;
    int   cnt = 0;   // wave-uniform (ballot/popcount)
    #pragma unroll
    for (int k = 0; k < NV; ++k) {
        #pragma unroll
        for (int j = 0; j < 4; ++j) {
            int e = v[k][j];
            sum += W2[e];                                   // branchless gather
            cnt += (int)__popcll(__ballot(e > 0));          // SALU count
        }
    }

    // 64-lane wave reduction, sum only (cnt already wave-uniform)
    #pragma unroll
    for (int off = 32; off > 0; off >>= 1)
        sum += __shfl_down(sum, off, 64);

    if (lane == 0)
        out[row] = sum / (float)cnt + b[0];
}

// Generic fallback (any S, any B): one block per row, runtime loop.
__global__ __launch_bounds__(256) void codon_freq_dot_kernel(
    const int* __restrict__ rna,
    const float* __restrict__ W,
    const float* __restrict__ b,
    float* __restrict__ out,
    int S)
{
    __shared__ float Wl[64];
    __shared__ float psum[4];
    __shared__ int   pcnt[4];

    const int row = blockIdx.x;
    const int t   = threadIdx.x;

    if (t < 64) Wl[t] = W[t];
    __syncthreads();

    const int* base = rna + (size_t)row * (size_t)S;

    float sum = 0.0f;
    int   cnt = 0;

    for (int i = t; i < S; i += 256) {
        int e = base[i];
        if (e > 0) { sum += Wl[e - 1]; ++cnt; }
    }

    #pragma unroll
    for (int off = 32; off > 0; off >>= 1) {
        sum += __shfl_down(sum, off, 64);
        cnt += __shfl_down(cnt, off, 64);
    }

    const int wave = t >> 6;
    const int lane = t & 63;
    if (lane == 0) { psum[wave] = sum; pcnt[wave] = cnt; }
    __syncthreads();

    if (t == 0) {
        float s = psum[0] + psum[1] + psum[2] + psum[3];
        int   c = pcnt[0] + pcnt[1] + pcnt[2] + pcnt[3];
        out[row] = s / (float)c + b[0];
    }
}

extern "C" void kernel_launch(void* const* d_in, const int* in_sizes, int n_in,
                              void* d_out, int out_size, void* d_ws, size_t ws_size,
                              hipStream_t stream) {
    const int*   rna = (const int*)d_in[0];
    // d_in[1] = tissue_id -- unused by the reference computation
    const float* W   = (const float*)d_in[2];
    const float* b   = (const float*)d_in[3];
    float*       out = (float*)d_out;

    const int B = out_size;              // 16384 rows (output is (B,1))
    const int S = in_sizes[0] / B;       // 2048 codons per row

    if (S == 2048 && (B & 3) == 0) {
        // 8 int4 per lane, 1 wave per row, 4 rows per block
        codon_rows_kernel<8><<<B / 4, 256, 0, stream>>>(rna, W, b, out, S);
    } else {
        codon_freq_dot_kernel<<<B, 256, 0, stream>>>(rna, W, b, out, S);
    }
}